// Round 9
// baseline (102.888 us; speedup 1.0000x reference)
//
#include <hip/hip_runtime.h>
#include <hip/hip_bf16.h>
#include <stdint.h>

#define E_ 8
#define H_ 1024
#define I_ 1024
#define T_ 8192
#define BM 128
#define BK 32
#define NKT 32

typedef __attribute__((ext_vector_type(4))) float f32x4;
typedef __attribute__((ext_vector_type(8))) short bf16x8;
typedef __attribute__((ext_vector_type(8))) unsigned short u16x8;

__device__ __forceinline__ unsigned short f2bf(float f) {
  union { float f; unsigned int u; } v; v.f = f;
  unsigned int lsb = (v.u >> 16) & 1u;
  v.u += 0x7fffu + lsb;          // RNE
  return (unsigned short)(v.u >> 16);
}

__device__ __forceinline__ void gload_lds16(const void* g, void* l) {
  __builtin_amdgcn_global_load_lds(
      (const __attribute__((address_space(1))) unsigned int*)g,
      (__attribute__((address_space(3))) unsigned int*)l,
      16, 0, 0);
}

// ------------- expert lookup -------------
__device__ __forceinline__ void find_tile(const int* counts, int ty,
                                          int& row_start, int& rows, int& expert) {
  int tacc = 0, off = 0;
  expert = 0; row_start = 0; rows = BM;
  #pragma unroll
  for (int e = 0; e < E_; ++e) {
    int c = counts[e];
    int te = (c + BM - 1) >> 7;
    if (ty >= tacc && ty < tacc + te) {
      expert = e;
      int lt = ty - tacc;
      row_start = off + lt * BM;
      rows = min(BM, c - lt * BM);
    }
    tacc += te; off += c;
  }
}

// =====================================================================
// convert_x: f32 -> bf16 streaming, float4 in / ushort4 out (16 KB/block)
// =====================================================================
__global__ __launch_bounds__(256) void convert_x(
    const float* __restrict__ x, unsigned short* __restrict__ xb) {
  int id = blockIdx.x;
  #pragma unroll
  for (int it = 0; it < 4; ++it) {
    int i = id * 4096 + it * 1024 + threadIdx.x * 4;
    float4 v = *reinterpret_cast<const float4*>(x + i);
    ushort4 o;
    o.x = f2bf(v.x); o.y = f2bf(v.y); o.z = f2bf(v.z); o.w = f2bf(v.w);
    *reinterpret_cast<ushort4*>(xb + i) = o;
  }
}

// ---------- transpose role v3: 16 B stores ----------
// [R][C] f32 -> [C][R] bf16 ; in-tile 128 rows x 64 cols per block (256 thr)
// loads: float4 (16 B/lane); LDS [128][65]; stores: ushort8 (16 B/lane)
__device__ __forceinline__ void transpose_role(const float* __restrict__ inp,
                                               unsigned short* __restrict__ outp,
                                               int R, int C, int bx, int by,
                                               float* tile /* [128*65] */) {
  int c0 = bx * 64, r0 = by * 128;
  int lc = threadIdx.x & 15;        // float4 col group (16 x 4 = 64 cols)
  int lrw = threadIdx.x >> 4;       // 0..15 rows per pass
  #pragma unroll
  for (int p = 0; p < 8; ++p) {
    int r = p * 16 + lrw;
    float4 v = *reinterpret_cast<const float4*>(
        inp + (size_t)(r0 + r) * C + c0 + lc * 4);
    float* t = &tile[r * 65 + lc * 4];
    t[0] = v.x; t[1] = v.y; t[2] = v.z; t[3] = v.w;
  }
  __syncthreads();
  int lq = threadIdx.x & 15;        // r-chunk (8 f32) within out row
  int co = threadIdx.x >> 4;        // 0..15 out-row groups per pass
  #pragma unroll
  for (int p = 0; p < 4; ++p) {
    int cc = p * 16 + co;           // 64 out rows
    u16x8 o;
    #pragma unroll
    for (int i = 0; i < 8; ++i)
      o[i] = f2bf(tile[(8 * lq + i) * 65 + cc]);
    *reinterpret_cast<u16x8*>(&outp[(size_t)(c0 + cc) * R + r0 + 8 * lq]) = o;
  }
}

// =====================================================================
// transpose_w: [0,2048) w1 [E][H][2I] -> [E][2I][H]; [2048,3072) w2
// =====================================================================
__global__ __launch_bounds__(256) void transpose_w(
    const float* __restrict__ w1, unsigned short* __restrict__ w1t,
    const float* __restrict__ w2, unsigned short* __restrict__ w2t) {
  __shared__ float tile[128 * 65];
  int id = blockIdx.x;
  if (id < 2048) {                          // w1: R=H_, C=2I -> 32 x 8 x 8
    int bx = id & 31, by = (id >> 5) & 7, bz = id >> 8;
    transpose_role(w1 + (size_t)bz * H_ * 2 * I_,
                   w1t + (size_t)bz * H_ * 2 * I_, H_, 2 * I_, bx, by, tile);
    return;
  }
  int tb = id - 2048;                       // w2: R=I_, C=H_ -> 16 x 8 x 8
  int bx = tb & 15, by = (tb >> 4) & 7, bz = tb >> 7;
  transpose_role(w2 + (size_t)bz * I_ * H_,
                 w2t + (size_t)bz * I_ * H_, I_, H_, bx, by, tile);
}

// =====================================================================
// GEMM1 + SwiGLU: X [T][H] bf16 x W1T [E][2I][H] bf16 -> Hout [T][I] bf16
// block: 128 rows x 256 B-rows; 4 waves (1m x 4n), wave 128 x 64, acc[8][4];
// BK=32; 3-buffer ring, vmcnt(12). grid 512 = 8 bn x 64 ty, XCD-swizzled.
// =====================================================================
#define GLDS (BM * BK + 256 * BK)           // shorts per ring buffer (24 KB)
__global__ __launch_bounds__(256, 2) void gemm1_swiglu(
    const unsigned short* __restrict__ X,
    const unsigned short* __restrict__ W1T,
    const int* __restrict__ counts,
    unsigned short* __restrict__ Hout) {
  __shared__ unsigned short pool[3 * GLDS];  // 72 KB
  int id = blockIdx.x;
  int swz = (id & 7) * 64 + (id >> 3);      // 512 % 8 == 0, bijective
  int bn = swz & 7;                          // h block (128 wide)
  int tyid = swz >> 3;                       // M tile 0..63
  int row_start, rows, expert;
  find_tile(counts, tyid, row_start, rows, expert);
  int tid = threadIdx.x, wid = tid >> 6, lane = tid & 63;
  const unsigned short* Wp = W1T + (size_t)expert * (2 * I_) * H_;

  f32x4 acc[8][4];
  #pragma unroll
  for (int m = 0; m < 8; ++m)
    #pragma unroll
    for (int n = 0; n < 4; ++n) acc[m][n] = {0.f, 0.f, 0.f, 0.f};

  int l4 = lane >> 2;
  int csw = ((lane & 3) ^ ((l4 >> 1) & 3)) * 8;   // pre-swizzled global k-chunk
  int lr = lane & 15;
  int ck = ((lane >> 4) ^ ((lr >> 1) & 3)) * 8;   // swizzled ds_read k-chunk

  // per-thread: 2 A + 4 B = 6 gload_lds per tile
#define STAGE1(buf, kt) do {                                                   \
    int k0 = (kt) * BK + csw;                                                  \
    unsigned short* Ab = pool + (buf) * GLDS;                                  \
    unsigned short* Bb = Ab + BM * BK;                                         \
    _Pragma("unroll")                                                          \
    for (int i = 0; i < 2; ++i) {                                              \
      int r = wid * 32 + i * 16;                                               \
      int gr = row_start + min(r + l4, rows - 1);                              \
      gload_lds16(X + (size_t)gr * H_ + k0, Ab + r * BK);                      \
    }                                                                          \
    _Pragma("unroll")                                                          \
    for (int i = 0; i < 4; ++i) {                                              \
      int r = wid * 64 + i * 16;                                               \
      int rb = r + l4;                                                         \
      int sub = rb & 63, ow = rb >> 6;                                         \
      int col = (sub < 32) ? (bn * 128 + ow * 32 + sub)                        \
                           : (I_ + bn * 128 + ow * 32 + sub - 32);             \
      gload_lds16(Wp + (size_t)col * H_ + k0, Bb + r * BK);                    \
    }                                                                          \
  } while (0)

  STAGE1(0, 0);
  STAGE1(1, 1);
  for (int kt = 0; kt < NKT; ++kt) {
    STAGE1((kt + 2) % 3, min(kt + 2, NKT - 1));
    asm volatile("s_waitcnt vmcnt(12)" ::: "memory");
    __builtin_amdgcn_sched_barrier(0);
    __builtin_amdgcn_s_barrier();
    const unsigned short* Ab = pool + (kt % 3) * GLDS;
    const unsigned short* Bb = Ab + BM * BK;
    bf16x8 a[8], b[4];
    #pragma unroll
    for (int m = 0; m < 8; ++m)
      a[m] = *reinterpret_cast<const bf16x8*>(&Ab[(m * 16 + lr) * BK + ck]);
    #pragma unroll
    for (int n = 0; n < 4; ++n)
      b[n] = *reinterpret_cast<const bf16x8*>(&Bb[(wid * 64 + n * 16 + lr) * BK + ck]);
    __builtin_amdgcn_s_setprio(1);
    #pragma unroll
    for (int m = 0; m < 8; ++m)
      #pragma unroll
      for (int n = 0; n < 4; ++n)
        acc[m][n] = __builtin_amdgcn_mfma_f32_16x16x32_bf16(a[m], b[n], acc[m][n], 0, 0, 0);
    __builtin_amdgcn_s_setprio(0);
    __builtin_amdgcn_s_barrier();
  }
#undef STAGE1

  int lq = lane >> 4;
  #pragma unroll
  for (int m = 0; m < 8; ++m)
    #pragma unroll
    for (int n = 0; n < 2; ++n) {
      f32x4 g = acc[m][n], u = acc[m][n + 2];
      #pragma unroll
      for (int r = 0; r < 4; ++r) {
        int rl = m * 16 + lq * 4 + r;
        if (rl < rows) {
          float gv = g[r];
          float hv = (gv / (1.f + __expf(-gv))) * u[r];
          Hout[(size_t)(row_start + rl) * I_ + bn * 128 + wid * 32 + n * 16 + lr] = f2bf(hv);
        }
      }
    }
}

// =====================================================================
// GEMM2: Hin [T][I] bf16 x W2T [E][H][I] bf16 -> Out [T][H] f32
// block 128 x 256, 4 waves (1m x 4n), wave 128x64, acc[8][4];
// 3-ring, vmcnt(12). grid 256 = 4 bn x 64 ty.
// =====================================================================
__global__ __launch_bounds__(256, 2) void gemm2(
    const unsigned short* __restrict__ Hin,
    const unsigned short* __restrict__ W2T,
    const int* __restrict__ counts,
    float* __restrict__ Out) {
  __shared__ unsigned short pool[3 * GLDS];  // 72 KB
  int id = blockIdx.x;
  int swz = (id & 7) * 32 + (id >> 3);       // 256 % 8 == 0
  int bn = swz & 3;                           // out col block (256 wide)
  int tyid = swz >> 2;
  int row_start, rows, expert;
  find_tile(counts, tyid, row_start, rows, expert);
  int tid = threadIdx.x, wid = tid >> 6, lane = tid & 63;
  const unsigned short* Wp = W2T + (size_t)expert * H_ * I_;

  f32x4 acc[8][4];
  #pragma unroll
  for (int m = 0; m < 8; ++m)
    #pragma unroll
    for (int n = 0; n < 4; ++n) acc[m][n] = {0.f, 0.f, 0.f, 0.f};

  int l4 = lane >> 2;
  int csw = ((lane & 3) ^ ((l4 >> 1) & 3)) * 8;
  int lr = lane & 15;
  int ck = ((lane >> 4) ^ ((lr >> 1) & 3)) * 8;

  // per-thread: 2 A + 4 B = 6 gload_lds per tile
#define STAGE2(buf, kt) do {                                                   \
    int k0 = (kt) * BK + csw;                                                  \
    unsigned short* Ab = pool + (buf) * GLDS;                                  \
    unsigned short* Bb = Ab + BM * BK;                                         \
    _Pragma("unroll")                                                          \
    for (int i = 0; i < 2; ++i) {                                              \
      int r = wid * 32 + i * 16;                                               \
      int gr = row_start + min(r + l4, rows - 1);                              \
      gload_lds16(Hin + (size_t)gr * I_ + k0, Ab + r * BK);                    \
    }                                                                          \
    _Pragma("unroll")                                                          \
    for (int i = 0; i < 4; ++i) {                                              \
      int r = wid * 64 + i * 16;                                               \
      int col = bn * 256 + r + l4;                                             \
      gload_lds16(Wp + (size_t)col * I_ + k0, Bb + r * BK);                    \
    }                                                                          \
  } while (0)

  STAGE2(0, 0);
  STAGE2(1, 1);
  for (int kt = 0; kt < NKT; ++kt) {
    STAGE2((kt + 2) % 3, min(kt + 2, NKT - 1));
    asm volatile("s_waitcnt vmcnt(12)" ::: "memory");
    __builtin_amdgcn_sched_barrier(0);
    __builtin_amdgcn_s_barrier();
    const unsigned short* Ab = pool + (kt % 3) * GLDS;
    const unsigned short* Bb = Ab + BM * BK;
    bf16x8 a[8], b[4];
    #pragma unroll
    for (int m = 0; m < 8; ++m)
      a[m] = *reinterpret_cast<const bf16x8*>(&Ab[(m * 16 + lr) * BK + ck]);
    #pragma unroll
    for (int n = 0; n < 4; ++n)
      b[n] = *reinterpret_cast<const bf16x8*>(&Bb[(wid * 64 + n * 16 + lr) * BK + ck]);
    __builtin_amdgcn_s_setprio(1);
    #pragma unroll
    for (int m = 0; m < 8; ++m)
      #pragma unroll
      for (int n = 0; n < 4; ++n)
        acc[m][n] = __builtin_amdgcn_mfma_f32_16x16x32_bf16(a[m], b[n], acc[m][n], 0, 0, 0);
    __builtin_amdgcn_s_setprio(0);
    __builtin_amdgcn_s_barrier();
  }
#undef STAGE2

  int lq = lane >> 4;
  #pragma unroll
  for (int m = 0; m < 8; ++m)
    #pragma unroll
    for (int n = 0; n < 4; ++n)
      #pragma unroll
      for (int r = 0; r < 4; ++r) {
        int rl = m * 16 + lq * 4 + r;
        if (rl < rows)
          Out[(size_t)(row_start + rl) * H_ + bn * 256 + wid * 64 + n * 16 + lr] =
              acc[m][n][r];
      }
}

extern "C" void kernel_launch(void* const* d_in, const int* in_sizes, int n_in,
                              void* d_out, int out_size, void* d_ws, size_t ws_size,
                              hipStream_t stream) {
  const float* x  = (const float*)d_in[0];
  const float* w1 = (const float*)d_in[1];   // [E][H][2I]
  const float* w2 = (const float*)d_in[2];   // [E][I][H]
  const int* counts = (const int*)d_in[3];
  float* out = (float*)d_out;

  char* ws = (char*)d_ws;
  unsigned short* xb  = (unsigned short*)ws;
  unsigned short* w1t = (unsigned short*)(ws + (size_t)T_ * H_ * 2);
  unsigned short* w2t = (unsigned short*)(ws + (size_t)T_ * H_ * 2
                                             + (size_t)E_ * 2 * I_ * H_ * 2);
  unsigned short* hbuf = (unsigned short*)(ws + (size_t)T_ * H_ * 2
                                              + (size_t)E_ * 2 * I_ * H_ * 2
                                              + (size_t)E_ * H_ * I_ * 2);

  // 1) preprocessing, split for attribution
  convert_x<<<2048, 256, 0, stream>>>(x, xb);
  transpose_w<<<3072, 256, 0, stream>>>(w1, w1t, w2, w2t);
  // 2) grouped GEMM1 + SwiGLU
  gemm1_swiglu<<<512, 256, 0, stream>>>(xb, w1t, counts, hbuf);
  // 3) grouped GEMM2
  gemm2<<<256, 256, 0, stream>>>(hbuf, w2t, counts, out);
}

// Round 10
// 101.844 us; speedup vs baseline: 1.0103x; 1.0103x over previous
//
#include <hip/hip_runtime.h>
#include <hip/hip_bf16.h>
#include <stdint.h>

#define E_ 8
#define H_ 1024
#define I_ 1024
#define T_ 8192
#define BM 128

typedef __attribute__((ext_vector_type(4))) float f32x4;
typedef __attribute__((ext_vector_type(8))) short bf16x8;
typedef __attribute__((ext_vector_type(8))) unsigned short u16x8;

__device__ __forceinline__ unsigned short f2bf(float f) {
  union { float f; unsigned int u; } v; v.f = f;
  unsigned int lsb = (v.u >> 16) & 1u;
  v.u += 0x7fffu + lsb;          // RNE
  return (unsigned short)(v.u >> 16);
}

__device__ __forceinline__ void gload_lds16(const void* g, void* l) {
  __builtin_amdgcn_global_load_lds(
      (const __attribute__((address_space(1))) unsigned int*)g,
      (__attribute__((address_space(3))) unsigned int*)l,
      16, 0, 0);
}

// ------------- expert lookup -------------
__device__ __forceinline__ void find_tile(const int* counts, int ty,
                                          int& row_start, int& rows, int& expert) {
  int tacc = 0, off = 0;
  expert = 0; row_start = 0; rows = BM;
  #pragma unroll
  for (int e = 0; e < E_; ++e) {
    int c = counts[e];
    int te = (c + BM - 1) >> 7;
    if (ty >= tacc && ty < tacc + te) {
      expert = e;
      int lt = ty - tacc;
      row_start = off + lt * BM;
      rows = min(BM, c - lt * BM);
    }
    tacc += te; off += c;
  }
}

// =====================================================================
// convert_x: f32 -> bf16 streaming, float4 in / ushort4 out (16 KB/block)
// =====================================================================
__global__ __launch_bounds__(256) void convert_x(
    const float* __restrict__ x, unsigned short* __restrict__ xb) {
  int id = blockIdx.x;
  #pragma unroll
  for (int it = 0; it < 4; ++it) {
    int i = id * 4096 + it * 1024 + threadIdx.x * 4;
    float4 v = *reinterpret_cast<const float4*>(x + i);
    ushort4 o;
    o.x = f2bf(v.x); o.y = f2bf(v.y); o.z = f2bf(v.z); o.w = f2bf(v.w);
    *reinterpret_cast<ushort4*>(xb + i) = o;
  }
}

// ---------- transpose role: 16 B loads / 16 B stores ----------
__device__ __forceinline__ void transpose_role(const float* __restrict__ inp,
                                               unsigned short* __restrict__ outp,
                                               int R, int C, int bx, int by,
                                               float* tile /* [128*65] */) {
  int c0 = bx * 64, r0 = by * 128;
  int lc = threadIdx.x & 15;
  int lrw = threadIdx.x >> 4;
  #pragma unroll
  for (int p = 0; p < 8; ++p) {
    int r = p * 16 + lrw;
    float4 v = *reinterpret_cast<const float4*>(
        inp + (size_t)(r0 + r) * C + c0 + lc * 4);
    float* t = &tile[r * 65 + lc * 4];
    t[0] = v.x; t[1] = v.y; t[2] = v.z; t[3] = v.w;
  }
  __syncthreads();
  int lq = threadIdx.x & 15;
  int co = threadIdx.x >> 4;
  #pragma unroll
  for (int p = 0; p < 4; ++p) {
    int cc = p * 16 + co;
    u16x8 o;
    #pragma unroll
    for (int i = 0; i < 8; ++i)
      o[i] = f2bf(tile[(8 * lq + i) * 65 + cc]);
    *reinterpret_cast<u16x8*>(&outp[(size_t)(c0 + cc) * R + r0 + 8 * lq]) = o;
  }
}

// =====================================================================
// transpose_w: [0,2048) w1 [E][H][2I] -> [E][2I][H]; [2048,3072) w2
// =====================================================================
__global__ __launch_bounds__(256) void transpose_w(
    const float* __restrict__ w1, unsigned short* __restrict__ w1t,
    const float* __restrict__ w2, unsigned short* __restrict__ w2t) {
  __shared__ float tile[128 * 65];
  int id = blockIdx.x;
  if (id < 2048) {
    int bx = id & 31, by = (id >> 5) & 7, bz = id >> 8;
    transpose_role(w1 + (size_t)bz * H_ * 2 * I_,
                   w1t + (size_t)bz * H_ * 2 * I_, H_, 2 * I_, bx, by, tile);
    return;
  }
  int tb = id - 2048;
  int bx = tb & 15, by = (tb >> 4) & 7, bz = tb >> 7;
  transpose_role(w2 + (size_t)bz * I_ * H_,
                 w2t + (size_t)bz * I_ * H_, I_, H_, bx, by, tile);
}

// =====================================================================
// 8-phase grouped GEMM template constants (both GEMMs):
// 512 thr (8 waves 2M x 4N), block 128 x 256, wave 64 x 64, acc[4][4];
// BK=64, 3-ring LDS (A 128x64 + B 256x64 bf16 = 48 KB/buf, 144 KB total);
// 4 phases/K-tile: {ds_read frags || stage part of tile t+2 -> barrier ->
// setprio 8xMFMA -> barrier}; vmcnt(6) once per K-tile at phase 3.
// LDS swizzle (BK=64, 128B rows): read chunk c' = c ^ (lr&7); staging
// source pre-swizzled with the same involution; gload_lds dest linear.
// =====================================================================
#define GBUF 24576           // shorts per ring buffer: (128+256)*64
#define GNKT 16              // 1024 / 64

__device__ __forceinline__ bf16x8 ldfrag(const unsigned short* b, int row, int ck) {
  return *reinterpret_cast<const bf16x8*>(&b[row * 64 + ck]);
}

// ---------------- GEMM1 + SwiGLU ----------------
// grid 512 = 8 bn x 64 ty, XCD-swizzled. B rows: per wave-col wc, 32 gate
// cols then 32 up cols -> acc[m][n] (n<2) gate pairs with acc[m][n+2] up.
__global__ __launch_bounds__(512, 1) void gemm1_swiglu(
    const unsigned short* __restrict__ X,
    const unsigned short* __restrict__ W1T,
    const int* __restrict__ counts,
    unsigned short* __restrict__ Hout) {
  __shared__ unsigned short pool[3 * GBUF];   // 144 KB
  int id = blockIdx.x;
  int swz = (id & 7) * 64 + (id >> 3);        // 512 % 8 == 0, bijective
  int bn = swz & 7;
  int tyid = swz >> 3;
  int row_start, rows, expert;
  find_tile(counts, tyid, row_start, rows, expert);
  int tid = threadIdx.x, w = tid >> 6, lane = tid & 63;
  int wr = w >> 2, wc = w & 3;
  const unsigned short* Wp = W1T + (size_t)expert * (2 * I_) * H_;

  f32x4 acc[4][4];
  #pragma unroll
  for (int m = 0; m < 4; ++m)
    #pragma unroll
    for (int n = 0; n < 4; ++n) acc[m][n] = {0.f, 0.f, 0.f, 0.f};

  int lr = lane & 15, hi = lane >> 4;
  int ck0 = (hi ^ (lr & 7)) * 8;              // k-half 0 swizzled chunk
  int ck1 = ((4 + hi) ^ (lr & 7)) * 8;        // k-half 1
  int sr = lane >> 3;                          // staging row in 8-row chunk
  int cgo = ((lane & 7) ^ sr) * 8;             // pre-swizzled global chunk

#define S1A(buf, kt, i) do {                                                   \
    int r = (w * 2 + (i)) * 8 + sr;                                            \
    int gr = row_start + min(r, rows - 1);                                     \
    gload_lds16(X + (size_t)gr * H_ + (kt) * 64 + cgo,                         \
                pool + (buf) * GBUF + (w * 2 + (i)) * 512);                    \
  } while (0)
#define S1B(buf, kt, i) do {                                                   \
    int rb = (w * 4 + (i)) * 8 + sr;                                           \
    int wcv = rb >> 6, sub = rb & 63;                                          \
    int col = (sub < 32) ? (bn * 128 + wcv * 32 + sub)                         \
                         : (I_ + bn * 128 + wcv * 32 + (sub - 32));            \
    gload_lds16(Wp + (size_t)col * H_ + (kt) * 64 + cgo,                       \
                pool + (buf) * GBUF + 8192 + (w * 4 + (i)) * 512);             \
  } while (0)

  S1A(0, 0, 0); S1A(0, 0, 1); S1B(0, 0, 0); S1B(0, 0, 1); S1B(0, 0, 2); S1B(0, 0, 3);
  S1A(1, 1, 0); S1A(1, 1, 1); S1B(1, 1, 0); S1B(1, 1, 1); S1B(1, 1, 2); S1B(1, 1, 3);
  asm volatile("s_waitcnt vmcnt(6)" ::: "memory");
  __builtin_amdgcn_sched_barrier(0);
  __builtin_amdgcn_s_barrier();

  for (int t = 0; t < GNKT; ++t) {
    const unsigned short* Ab = pool + (t % 3) * GBUF;
    const unsigned short* Bb = Ab + 8192;
    int dst = (t + 2) % 3;
    int nk = t + 2;
    bool pre = (nk < GNKT);
    bf16x8 bf[4], af[2];
    // -------- phase 0: k-half 0, m 0-1 --------
    #pragma unroll
    for (int n = 0; n < 4; ++n) bf[n] = ldfrag(Bb, wc * 64 + n * 16 + lr, ck0);
    af[0] = ldfrag(Ab, wr * 64 + lr, ck0);
    af[1] = ldfrag(Ab, wr * 64 + 16 + lr, ck0);
    if (pre) S1A(dst, nk, 0);
    __builtin_amdgcn_s_barrier();
    __builtin_amdgcn_s_setprio(1);
    #pragma unroll
    for (int m = 0; m < 2; ++m)
      #pragma unroll
      for (int n = 0; n < 4; ++n)
        acc[m][n] = __builtin_amdgcn_mfma_f32_16x16x32_bf16(af[m], bf[n], acc[m][n], 0, 0, 0);
    __builtin_amdgcn_s_setprio(0);
    __builtin_amdgcn_s_barrier();
    // -------- phase 1: k-half 0, m 2-3 --------
    af[0] = ldfrag(Ab, wr * 64 + 32 + lr, ck0);
    af[1] = ldfrag(Ab, wr * 64 + 48 + lr, ck0);
    if (pre) S1A(dst, nk, 1);
    __builtin_amdgcn_s_barrier();
    __builtin_amdgcn_s_setprio(1);
    #pragma unroll
    for (int m = 0; m < 2; ++m)
      #pragma unroll
      for (int n = 0; n < 4; ++n)
        acc[m + 2][n] = __builtin_amdgcn_mfma_f32_16x16x32_bf16(af[m], bf[n], acc[m + 2][n], 0, 0, 0);
    __builtin_amdgcn_s_setprio(0);
    __builtin_amdgcn_s_barrier();
    // -------- phase 2: k-half 1, m 0-1 --------
    #pragma unroll
    for (int n = 0; n < 4; ++n) bf[n] = ldfrag(Bb, wc * 64 + n * 16 + lr, ck1);
    af[0] = ldfrag(Ab, wr * 64 + lr, ck1);
    af[1] = ldfrag(Ab, wr * 64 + 16 + lr, ck1);
    if (pre) { S1B(dst, nk, 0); S1B(dst, nk, 1); }
    __builtin_amdgcn_s_barrier();
    __builtin_amdgcn_s_setprio(1);
    #pragma unroll
    for (int m = 0; m < 2; ++m)
      #pragma unroll
      for (int n = 0; n < 4; ++n)
        acc[m][n] = __builtin_amdgcn_mfma_f32_16x16x32_bf16(af[m], bf[n], acc[m][n], 0, 0, 0);
    __builtin_amdgcn_s_setprio(0);
    __builtin_amdgcn_s_barrier();
    // -------- phase 3: k-half 1, m 2-3 (+ vmcnt guard) --------
    af[0] = ldfrag(Ab, wr * 64 + 32 + lr, ck1);
    af[1] = ldfrag(Ab, wr * 64 + 48 + lr, ck1);
    if (pre) {
      S1B(dst, nk, 2); S1B(dst, nk, 3);
      asm volatile("s_waitcnt vmcnt(6)" ::: "memory");
    } else {
      asm volatile("s_waitcnt vmcnt(0)" ::: "memory");
    }
    __builtin_amdgcn_sched_barrier(0);
    __builtin_amdgcn_s_barrier();
    __builtin_amdgcn_s_setprio(1);
    #pragma unroll
    for (int m = 0; m < 2; ++m)
      #pragma unroll
      for (int n = 0; n < 4; ++n)
        acc[m + 2][n] = __builtin_amdgcn_mfma_f32_16x16x32_bf16(af[m], bf[n], acc[m + 2][n], 0, 0, 0);
    __builtin_amdgcn_s_setprio(0);
    __builtin_amdgcn_s_barrier();
  }
#undef S1A
#undef S1B

  int lq = lane >> 4;
  #pragma unroll
  for (int m = 0; m < 4; ++m)
    #pragma unroll
    for (int n = 0; n < 2; ++n) {
      f32x4 g = acc[m][n], u = acc[m][n + 2];
      #pragma unroll
      for (int r = 0; r < 4; ++r) {
        int rl = wr * 64 + m * 16 + lq * 4 + r;
        if (rl < rows) {
          float gv = g[r];
          float hv = (gv / (1.f + __expf(-gv))) * u[r];
          Hout[(size_t)(row_start + rl) * I_ + bn * 128 + wc * 32 + n * 16 + lr] = f2bf(hv);
        }
      }
    }
}

// ---------------- GEMM2 (same 8-phase template) ----------------
// grid 256 = 4 bn x 64 ty; B LDS row rb = output col bn*256 + rb.
__global__ __launch_bounds__(512, 1) void gemm2(
    const unsigned short* __restrict__ Hin,
    const unsigned short* __restrict__ W2T,
    const int* __restrict__ counts,
    float* __restrict__ Out) {
  __shared__ unsigned short pool[3 * GBUF];   // 144 KB
  int id = blockIdx.x;
  int swz = (id & 7) * 32 + (id >> 3);        // 256 % 8 == 0
  int bn = swz & 3;
  int tyid = swz >> 2;
  int row_start, rows, expert;
  find_tile(counts, tyid, row_start, rows, expert);
  int tid = threadIdx.x, w = tid >> 6, lane = tid & 63;
  int wr = w >> 2, wc = w & 3;
  const unsigned short* Wp = W2T + (size_t)expert * H_ * I_;

  f32x4 acc[4][4];
  #pragma unroll
  for (int m = 0; m < 4; ++m)
    #pragma unroll
    for (int n = 0; n < 4; ++n) acc[m][n] = {0.f, 0.f, 0.f, 0.f};

  int lr = lane & 15, hi = lane >> 4;
  int ck0 = (hi ^ (lr & 7)) * 8;
  int ck1 = ((4 + hi) ^ (lr & 7)) * 8;
  int sr = lane >> 3;
  int cgo = ((lane & 7) ^ sr) * 8;

#define S2A(buf, kt, i) do {                                                   \
    int r = (w * 2 + (i)) * 8 + sr;                                            \
    int gr = row_start + min(r, rows - 1);                                     \
    gload_lds16(Hin + (size_t)gr * I_ + (kt) * 64 + cgo,                       \
                pool + (buf) * GBUF + (w * 2 + (i)) * 512);                    \
  } while (0)
#define S2B(buf, kt, i) do {                                                   \
    int rb = (w * 4 + (i)) * 8 + sr;                                           \
    int col = bn * 256 + rb;                                                   \
    gload_lds16(Wp + (size_t)col * I_ + (kt) * 64 + cgo,                       \
                pool + (buf) * GBUF + 8192 + (w * 4 + (i)) * 512);             \
  } while (0)

  S2A(0, 0, 0); S2A(0, 0, 1); S2B(0, 0, 0); S2B(0, 0, 1); S2B(0, 0, 2); S2B(0, 0, 3);
  S2A(1, 1, 0); S2A(1, 1, 1); S2B(1, 1, 0); S2B(1, 1, 1); S2B(1, 1, 2); S2B(1, 1, 3);
  asm volatile("s_waitcnt vmcnt(6)" ::: "memory");
  __builtin_amdgcn_sched_barrier(0);
  __builtin_amdgcn_s_barrier();

  for (int t = 0; t < GNKT; ++t) {
    const unsigned short* Ab = pool + (t % 3) * GBUF;
    const unsigned short* Bb = Ab + 8192;
    int dst = (t + 2) % 3;
    int nk = t + 2;
    bool pre = (nk < GNKT);
    bf16x8 bf[4], af[2];
    // phase 0
    #pragma unroll
    for (int n = 0; n < 4; ++n) bf[n] = ldfrag(Bb, wc * 64 + n * 16 + lr, ck0);
    af[0] = ldfrag(Ab, wr * 64 + lr, ck0);
    af[1] = ldfrag(Ab, wr * 64 + 16 + lr, ck0);
    if (pre) S2A(dst, nk, 0);
    __builtin_amdgcn_s_barrier();
    __builtin_amdgcn_s_setprio(1);
    #pragma unroll
    for (int m = 0; m < 2; ++m)
      #pragma unroll
      for (int n = 0; n < 4; ++n)
        acc[m][n] = __builtin_amdgcn_mfma_f32_16x16x32_bf16(af[m], bf[n], acc[m][n], 0, 0, 0);
    __builtin_amdgcn_s_setprio(0);
    __builtin_amdgcn_s_barrier();
    // phase 1
    af[0] = ldfrag(Ab, wr * 64 + 32 + lr, ck0);
    af[1] = ldfrag(Ab, wr * 64 + 48 + lr, ck0);
    if (pre) S2A(dst, nk, 1);
    __builtin_amdgcn_s_barrier();
    __builtin_amdgcn_s_setprio(1);
    #pragma unroll
    for (int m = 0; m < 2; ++m)
      #pragma unroll
      for (int n = 0; n < 4; ++n)
        acc[m + 2][n] = __builtin_amdgcn_mfma_f32_16x16x32_bf16(af[m], bf[n], acc[m + 2][n], 0, 0, 0);
    __builtin_amdgcn_s_setprio(0);
    __builtin_amdgcn_s_barrier();
    // phase 2
    #pragma unroll
    for (int n = 0; n < 4; ++n) bf[n] = ldfrag(Bb, wc * 64 + n * 16 + lr, ck1);
    af[0] = ldfrag(Ab, wr * 64 + lr, ck1);
    af[1] = ldfrag(Ab, wr * 64 + 16 + lr, ck1);
    if (pre) { S2B(dst, nk, 0); S2B(dst, nk, 1); }
    __builtin_amdgcn_s_barrier();
    __builtin_amdgcn_s_setprio(1);
    #pragma unroll
    for (int m = 0; m < 2; ++m)
      #pragma unroll
      for (int n = 0; n < 4; ++n)
        acc[m][n] = __builtin_amdgcn_mfma_f32_16x16x32_bf16(af[m], bf[n], acc[m][n], 0, 0, 0);
    __builtin_amdgcn_s_setprio(0);
    __builtin_amdgcn_s_barrier();
    // phase 3 (+ vmcnt guard)
    af[0] = ldfrag(Ab, wr * 64 + 32 + lr, ck1);
    af[1] = ldfrag(Ab, wr * 64 + 48 + lr, ck1);
    if (pre) {
      S2B(dst, nk, 2); S2B(dst, nk, 3);
      asm volatile("s_waitcnt vmcnt(6)" ::: "memory");
    } else {
      asm volatile("s_waitcnt vmcnt(0)" ::: "memory");
    }
    __builtin_amdgcn_sched_barrier(0);
    __builtin_amdgcn_s_barrier();
    __builtin_amdgcn_s_setprio(1);
    #pragma unroll
    for (int m = 0; m < 2; ++m)
      #pragma unroll
      for (int n = 0; n < 4; ++n)
        acc[m + 2][n] = __builtin_amdgcn_mfma_f32_16x16x32_bf16(af[m], bf[n], acc[m + 2][n], 0, 0, 0);
    __builtin_amdgcn_s_setprio(0);
    __builtin_amdgcn_s_barrier();
  }
#undef S2A
#undef S2B

  int lq = lane >> 4;
  #pragma unroll
  for (int m = 0; m < 4; ++m)
    #pragma unroll
    for (int n = 0; n < 4; ++n)
      #pragma unroll
      for (int r = 0; r < 4; ++r) {
        int rl = wr * 64 + m * 16 + lq * 4 + r;
        if (rl < rows)
          Out[(size_t)(row_start + rl) * H_ + bn * 256 + wc * 64 + n * 16 + lr] =
              acc[m][n][r];
      }
}

extern "C" void kernel_launch(void* const* d_in, const int* in_sizes, int n_in,
                              void* d_out, int out_size, void* d_ws, size_t ws_size,
                              hipStream_t stream) {
  const float* x  = (const float*)d_in[0];
  const float* w1 = (const float*)d_in[1];   // [E][H][2I]
  const float* w2 = (const float*)d_in[2];   // [E][I][H]
  const int* counts = (const int*)d_in[3];
  float* out = (float*)d_out;

  char* ws = (char*)d_ws;
  unsigned short* xb  = (unsigned short*)ws;
  unsigned short* w1t = (unsigned short*)(ws + (size_t)T_ * H_ * 2);
  unsigned short* w2t = (unsigned short*)(ws + (size_t)T_ * H_ * 2
                                             + (size_t)E_ * 2 * I_ * H_ * 2);
  unsigned short* hbuf = (unsigned short*)(ws + (size_t)T_ * H_ * 2
                                              + (size_t)E_ * 2 * I_ * H_ * 2
                                              + (size_t)E_ * H_ * I_ * 2);

  // 1) preprocessing
  convert_x<<<2048, 256, 0, stream>>>(x, xb);
  transpose_w<<<3072, 256, 0, stream>>>(w1, w1t, w2, w2t);
  // 2) grouped GEMM1 + SwiGLU (8-phase)
  gemm1_swiglu<<<512, 512, 0, stream>>>(xb, w1t, counts, hbuf);
  // 3) grouped GEMM2 (8-phase)
  gemm2<<<256, 512, 0, stream>>>(hbuf, w2t, counts, out);
}